// Round 19
// baseline (41.463 us; speedup 1.0000x reference)
//
#include <hip/hip_runtime.h>

// LQActiv forward: 2-bit quantization + least-squares basis refit.
// Output layout: [N floats wq][2 floats new_basis].
//
// Round 19: final dose-curve trim on the fused kernel (r18: 41.2us,
// fused pass ~38.5 vs 32.5 copy floor; gap == flat-VALU dose).
//  (a) cbig counted via __ballot + s_bcnt on the SCALAR pipe ('big' is
//      already an sgpr mask from 2 v_cmp + s_or) — deletes the per-lane
//      cndmask+int-add. Lane 0 of each wave participates in every
//      iteration its wave executes (smallest i), so lane 0's count is the
//      complete wave count, and lane 0 writes the wave's LDS slot.
//  (b) per-component accumulators (sabsX..W / sbigX..W) — break the
//      4-deep loop-carried add chain into 4 independent 1-add chains.
//   K1 lq_fused: cached load + NT store; q out + 3 partials/block.
//   K2 lq_final: f64 reduce of 3 columns + symmetric algebra + 2x2 solve.
// Fallback if regression: round-18 config (41.2us).

#define NBLOCKS 2048
#define NTHREADS 256

typedef float fvec4 __attribute__((ext_vector_type(4)));

// ---- K1: fused quantize + stats (flat web, scalar-pipe counting) ----
__global__ __launch_bounds__(NTHREADS) void lq_fused(
    const float* __restrict__ x, const float* __restrict__ basis,
    float* __restrict__ out, float* __restrict__ partials, int n, int n4) {
  const float v0 = basis[0], v1 = basis[1];
  float lev[4] = {-v0 - v1, -v0 + v1, v0 - v1, v0 + v1};
#define CSWAP(i, j)                                          \
  if (lev[i] > lev[j]) { float t = lev[i]; lev[i] = lev[j]; lev[j] = t; }
  CSWAP(0, 1) CSWAP(2, 3) CSWAP(0, 2) CSWAP(1, 3) CSWAP(1, 2)
#undef CSWAP
  const float hi = lev[3];                    // +(|v0|+|v1|)
  const float lo = lev[2];                    // +||v0|-|v1||
  const float vm = 0.5f * (lev[2] + lev[3]);  // T2 (= -T0 by symmetry)
  const float nvm = -vm;

  // per-component accumulators: independent 1-add chains per iteration
  float sabsX = 0.f, sabsY = 0.f, sabsZ = 0.f, sabsW = 0.f;
  float sbigX = 0.f, sbigY = 0.f, sbigZ = 0.f, sbigW = 0.f;
  unsigned long long cnt = 0;  // wave-uniform ballot popcounts (lane 0 authoritative)

  // flat per-element web; 'big' mask counted on the scalar pipe
  auto proc = [&](float w, float& sabs_c, float& sbig_c) -> float {
    const bool big = (w > vm) | (w <= nvm);  // exact searchsorted edges
    const float aw = __builtin_fabsf(w);
    sabs_c += aw;
    sbig_c += big ? aw : 0.f;
    cnt += __popcll(__ballot(big));          // scalar: s_bcnt1 of the cmp mask
    const float mag = big ? hi : lo;
    return __builtin_copysignf(mag, w);
  };

  const fvec4* __restrict__ x4 = (const fvec4*)x;
  fvec4* __restrict__ o4 = (fvec4*)out;
  const int tid = blockIdx.x * blockDim.x + threadIdx.x;
  const int stride = gridDim.x * blockDim.x;
  for (int i = tid; i < n4; i += stride) {
    fvec4 w = x4[i];  // cached load
    fvec4 q;
    q.x = proc(w.x, sabsX, sbigX);
    q.y = proc(w.y, sabsY, sbigY);
    q.z = proc(w.z, sabsZ, sbigZ);
    q.w = proc(w.w, sabsW, sbigW);
    __builtin_nontemporal_store(q, &o4[i]);
  }
  // scalar tail (N divisible by 4; kept for safety)
  for (int k = n4 * 4 + tid; k < n; k += stride) {
    out[k] = proc(x[k], sabsX, sbigX);
  }

  // merge component accumulators, then wave shfl + LDS block reduce
  float sabs = (sabsX + sabsY) + (sabsZ + sabsW);
  float sbig = (sbigX + sbigY) + (sbigZ + sbigW);
  for (int off = 32; off; off >>= 1) {
    sabs += __shfl_down(sabs, off);
    sbig += __shfl_down(sbig, off);
  }
  __shared__ float red[3][NTHREADS / 64];
  const int lane = threadIdx.x & 63;
  const int wid = threadIdx.x >> 6;
  if (lane == 0) {
    red[0][wid] = sabs;
    red[1][wid] = sbig;
    red[2][wid] = (float)cnt;  // lane 0 saw every ballot its wave issued
  }
  __syncthreads();
  if (threadIdx.x < 3) {
    float r = 0.f;
#pragma unroll
    for (int w = 0; w < NTHREADS / 64; ++w) r += red[threadIdx.x][w];
    partials[3 * blockIdx.x + threadIdx.x] = r;
  }
}

// ---- K2: reduce 3 columns + symmetric algebra + 2x2 solve (r17) ----
__global__ __launch_bounds__(NTHREADS) void lq_final(
    const float* __restrict__ partials, const float* __restrict__ basis,
    float* __restrict__ out_basis, int n, int nparts) {
  double SA = 0, SB = 0, CB = 0;
  for (int i = threadIdx.x; i < nparts; i += blockDim.x) {
    SA += (double)partials[3 * i + 0];
    SB += (double)partials[3 * i + 1];
    CB += (double)partials[3 * i + 2];
  }
  for (int off = 32; off; off >>= 1) {
    SA += __shfl_down(SA, off);
    SB += __shfl_down(SB, off);
    CB += __shfl_down(CB, off);
  }
  __shared__ double red[3][NTHREADS / 64];
  const int lane = threadIdx.x & 63;
  const int wid = threadIdx.x >> 6;
  if (lane == 0) {
    red[0][wid] = SA;
    red[1][wid] = SB;
    red[2][wid] = CB;
  }
  __syncthreads();
  if (threadIdx.x == 0) {
    double sabs = 0, sbig = 0, cbig = 0;
#pragma unroll
    for (int w = 0; w < NTHREADS / 64; ++w) {
      sabs += red[0][w];
      sbig += red[1][w];
      cbig += red[2][w];
    }
    // re-derive sorted levels + encodings from basis
    const float v0 = basis[0], v1 = basis[1];
    float lev[4] = {-v0 - v1, -v0 + v1, v0 - v1, v0 + v1};
    float e0[4] = {-1.f, -1.f, 1.f, 1.f};
    float e1[4] = {-1.f, 1.f, -1.f, 1.f};
#define CSWAP(i, j)                                                   \
    if (lev[i] > lev[j]) {                                            \
      float t = lev[i]; lev[i] = lev[j]; lev[j] = t;                  \
      t = e0[i]; e0[i] = e0[j]; e0[j] = t;                            \
      t = e1[i]; e1[i] = e1[j]; e1[j] = t;                            \
    }
    CSWAP(0, 1) CSWAP(2, 3) CSWAP(0, 2) CSWAP(1, 3) CSWAP(1, 2)
#undef CSWAP
    // encodings of +hi (idx 3) and +lo (idx 2); enc(-L) = -enc(+L)
    const double s0h = e0[3], s1h = e1[3];
    const double s0l = e0[2], s1l = e1[2];
    const double N = (double)n;
    const double slo = sabs - sbig;  // sum_{small} |w|
    const double clo = N - cbig;     // #small
    const double Sb0 = s0h * sbig + s0l * slo;
    const double Sb1 = s1h * sbig + s1l * slo;
    const double S01 = (s0h * s1h) * cbig + (s0l * s1l) * clo;
    // A = [[N, S01],[S01, N]]; v = A^{-1} b; new_basis = 0.9*basis + 0.1*v
    const double det = N * N - S01 * S01;
    const double nv0 = (N * Sb0 - S01 * Sb1) / det;
    const double nv1 = (N * Sb1 - S01 * Sb0) / det;
    out_basis[0] = (float)(0.9 * (double)v0 + 0.1 * nv0);
    out_basis[1] = (float)(0.9 * (double)v1 + 0.1 * nv1);
  }
}

extern "C" void kernel_launch(void* const* d_in, const int* in_sizes, int n_in,
                              void* d_out, int out_size, void* d_ws, size_t ws_size,
                              hipStream_t stream) {
  const float* x = (const float*)d_in[0];
  const float* basis = (const float*)d_in[1];
  float* out = (float*)d_out;
  const int n = in_sizes[0];
  float* partials = (float*)d_ws;  // nblocks * 3 floats

  int nblocks = NBLOCKS;
  const int maxb = (int)(ws_size / (3 * sizeof(float)));
  if (nblocks > maxb) nblocks = maxb;
  if (nblocks < 1) nblocks = 1;

  const int n4 = n / 4;
  lq_fused<<<nblocks, NTHREADS, 0, stream>>>(x, basis, out, partials, n, n4);
  lq_final<<<1, NTHREADS, 0, stream>>>(partials, basis, out + n, n, nblocks);
}